// Round 12
// baseline (164.273 us; speedup 1.0000x reference)
//
#include <hip/hip_runtime.h>
#include <hip/hip_bf16.h>

typedef __attribute__((ext_vector_type(4))) short bf16x4;
typedef __attribute__((ext_vector_type(16))) float f32x16;

#define SCALE 0.35355339059327373f
#define LOG2E 1.4426950408889634f

struct ProjW { const float* w[6]; const float* b[6]; };

template<typename T, typename F>
__device__ inline T bcast(F f) { union { F a; T b; } u; u.a = f; return u.b; }

// truncating bf16 pack: lo16 = bf16(a), hi16 = bf16(b)
__device__ inline unsigned tpk2(float a, float b) {
  return (__float_as_uint(a) >> 16) | (__float_as_uint(b) & 0xffff0000u);
}

__device__ inline float fast_exp2(float x) {
  float r;
  asm("v_exp_f32 %0, %1" : "=v"(r) : "v"(x));
  return r;
}

// ---- pack geo_mask [512][512] int -> bitmask [512][16] u32 ----
__global__ void k_pack_mask(const int* __restrict__ mask, unsigned* __restrict__ mbw) {
  int w = blockIdx.x * 256 + threadIdx.x;   // 0..8191
  int n = w >> 4, wi = w & 15;
  const int* mp = mask + n * 512 + wi * 32;
  unsigned bits = 0u;
  #pragma unroll
  for (int j = 0; j < 32; ++j) bits |= (mp[j] != 0) ? (1u << j) : 0u;
  mbw[w] = bits;
}

// ---- fused weights: wfb[p*32+c][68] bf16 = (W_p*W1) row c ; bfv[p][32] f32 ----
__global__ void k_wfuse(ProjW pw, const float* __restrict__ w1, const float* __restrict__ b1,
                        ushort* __restrict__ wfb, float* __restrict__ bfv) {
  int p = blockIdx.x;       // 0..5
  int d = threadIdx.x;      // 0..63
  const float* W = pw.w[p];
  float sc = (p % 3 == 0) ? SCALE * LOG2E : 1.0f;   // fold softmax scale + log2e into q
  float col[32];
  #pragma unroll
  for (int e = 0; e < 32; ++e) col[e] = w1[e * 64 + d];
  for (int c = 0; c < 32; ++c) {
    float a = 0.f;
    #pragma unroll
    for (int e = 0; e < 32; ++e) a = fmaf(W[c * 32 + e], col[e], a);
    __hip_bfloat16 hb = __float2bfloat16(a * sc);
    wfb[(p * 32 + c) * 68 + d] = *(ushort*)&hb;
  }
  if (d < 32) {
    float a = pw.b[p][d];
    #pragma unroll
    for (int e = 0; e < 32; ++e) a = fmaf(W[d * 32 + e], b1[e], a);
    bfv[p * 32 + d] = a * sc;
  }
}

// ---- MFMA projections: grid (bt=96, ch=8), 384 thr = 6 waves (wave = proj ci) ----
__global__ void __launch_bounds__(384) k_qkv(const float* __restrict__ x,
    const ushort* __restrict__ wfb, const float* __restrict__ bfv,
    ushort* __restrict__ Qb, ushort* __restrict__ Kb, ushort* __restrict__ Vt) {
  __shared__ __align__(16) ushort Wl[192 * 68];   // 25.5 KB
  int bt = blockIdx.x, ch = blockIdx.y;
  int tid = threadIdx.x;
  int b = bt / 12, t = bt - b * 12;
  for (int i = tid; i < 6528; i += 384)
    ((unsigned*)Wl)[i] = ((const unsigned*)wfb)[i];
  __syncthreads();

  int lane = tid & 63, ci = tid >> 6;     // ci = p, wave-uniform
  int lo = lane & 31, hi = lane >> 5;
  int blk = ci / 3, m = ci - blk * 3;

  bf16x4 af[8];
  #pragma unroll
  for (int ks = 0; ks < 8; ++ks)
    af[ks] = *(const bf16x4*)&Wl[(32 * ci + lo) * 68 + 8 * ks + 4 * hi];

  float bias[16];
  #pragma unroll
  for (int r = 0; r < 16; ++r)
    bias[r] = bfv[ci * 32 + (r & 3) + 8 * (r >> 2) + 4 * hi];

  const float* xb = x + ((size_t)b * 768 + t) * 512;   // + d*6144 + n
  for (int tile = 0; tile < 2; ++tile) {
    int n = ch * 64 + tile * 32 + lo;
    uint2 bfr[8];
    #pragma unroll
    for (int ks = 0; ks < 8; ++ks) {
      int d0 = 8 * ks + 4 * hi;
      float x0 = xb[(size_t)(d0 + 0) * 6144 + n];
      float x1 = xb[(size_t)(d0 + 1) * 6144 + n];
      float x2 = xb[(size_t)(d0 + 2) * 6144 + n];
      float x3 = xb[(size_t)(d0 + 3) * 6144 + n];
      bfr[ks] = make_uint2(tpk2(x0, x1), tpk2(x2, x3));
    }
    f32x16 acc;
    #pragma unroll
    for (int i = 0; i < 16; ++i) acc[i] = 0.f;
    #pragma unroll
    for (int ks = 0; ks < 8; ++ks)
      acc = __builtin_amdgcn_mfma_f32_32x32x8bf16_1k(af[ks], bcast<bf16x4>(bfr[ks]), acc, 0, 0, 0);
    #pragma unroll
    for (int r = 0; r < 16; ++r) acc[r] += bias[r];

    if (m < 2) {
      ushort* dst = (m == 0) ? Qb : Kb;
      #pragma unroll
      for (int h = 0; h < 4; ++h) {
        size_t inst = ((size_t)blk * 96 + bt) * 4 + h;
        unsigned u0 = tpk2(acc[4*h + 0], acc[4*h + 1]);
        unsigned u1 = tpk2(acc[4*h + 2], acc[4*h + 3]);
        unsigned u0x = __shfl_xor(u0, 32);
        unsigned u1x = __shfl_xor(u1, 32);
        if (hi == 0) {
          uint4 u = make_uint4(u0, u1, u0x, u1x);
          *(uint4*)(dst + (inst * 512 + n) * 8) = u;
        }
      }
    } else {
      #pragma unroll
      for (int j = 0; j < 8; ++j) {
        int r = 2 * j;
        int h = r >> 2;
        int dd = (r & 3) + 4 * hi;
        size_t inst = ((size_t)blk * 96 + bt) * 4 + h;
        unsigned u = tpk2(acc[r], acc[r + 1]);
        Vt[(inst * 8 + dd) * 512 + n]     = (ushort)(u & 0xffffu);
        Vt[(inst * 8 + dd + 1) * 512 + n] = (ushort)(u >> 16);
      }
    }
  }
}

// ---- MFMA attention: grid (h=4, bt=96, blk=2), 512 thr = 8 waves, 64 q-rows/wave ----
// K frags read straight from global (coalesced, L1-resident); V^T staged in LDS.
// Output written to obuf in the faithful-reshape flat order (f = ht*4096 + q*8 + d).
__global__ void __launch_bounds__(512) k_attn(const ushort* __restrict__ Qb,
    const ushort* __restrict__ Kb, const ushort* __restrict__ Vt,
    const unsigned* __restrict__ mbw, float* __restrict__ obuf) {
  __shared__ __align__(16) ushort Vl[9 * 520];    // V^T rows 0-7 + ones row 8
  int h = blockIdx.x, bt = blockIdx.y, blk = blockIdx.z;
  int tid = threadIdx.x;
  size_t inst = ((size_t)blk * 96 + bt) * 4 + h;

  { // stage V^T + ones row
    const ushort* vp = Vt + inst * 4096;
    #pragma unroll
    for (int d = 0; d < 8; ++d) Vl[d * 520 + tid] = vp[d * 512 + tid];
    Vl[8 * 520 + tid] = 0x3F80;   // bf16 1.0
  }
  __syncthreads();

  int lane = tid & 63, lo = lane & 31, hi = lane >> 5, w = tid >> 6;
  int qbase = w * 64;
  const ushort* kbase = Kb + inst * 4096;   // K[n][8]

  // Q fragments (B-operand of QK): lane holds Q[q][4*hi + i]
  bf16x4 qf[2];
  #pragma unroll
  for (int s = 0; s < 2; ++s) {
    int q = qbase + s * 32 + lo;
    qf[s] = bcast<bf16x4>(*(const uint2*)(Qb + inst * 4096 + q * 8 + hi * 4));
  }

  f32x16 acc[2], zc;
  #pragma unroll
  for (int i = 0; i < 16; ++i) { acc[0][i] = 0.f; acc[1][i] = 0.f; zc[i] = 0.f; }

  for (int t16 = 0; t16 < 16; ++t16) {
    // K fragment (A-operand) from global: lane reads 8B of row t16*32+lo
    bf16x4 kf = bcast<bf16x4>(*(const uint2*)(kbase + (t16 * 32 + lo) * 8 + 4 * hi));
    // V^T fragments (A-operand of AV): lane holds V^T[lo][kv = t16*32 + 8c + 4hi + i]
    bf16x4 vf[4];
    int vrow = (lo < 8 ? lo : 8) * 520 + t16 * 32 + 4 * hi;
    #pragma unroll
    for (int c = 0; c < 4; ++c) {
      uint2 vv = *(const uint2*)&Vl[vrow + 8 * c];
      if (lo > 8) { vv.x = 0u; vv.y = 0u; }   // rows 9..31 of A are zero
      vf[c] = bcast<bf16x4>(vv);
    }
    #pragma unroll
    for (int s = 0; s < 2; ++s) {
      // S^T tile = K · Q^T : D[kv][q], lane = q-col, regs = kv-rows
      f32x16 st = __builtin_amdgcn_mfma_f32_32x32x8bf16_1k(kf, qf[s], zc, 0, 0, 0);
      unsigned mwh = 0u;
      if (blk == 1) {
        int q = qbase + s * 32 + lo;
        mwh = mbw[q * 16 + t16] >> (4 * hi);
      }
      unsigned u[8];
      #pragma unroll
      for (int j = 0; j < 8; ++j) {
        float p0 = fast_exp2(st[2*j]);
        float p1 = fast_exp2(st[2*j+1]);
        if (blk == 1) {
          int c0 = ((2*j) & 3) + 8 * ((2*j) >> 2);
          if ((mwh >> c0) & 1u) p0 = 0.f;
          if ((mwh >> (c0 + 1)) & 1u) p1 = 0.f;
        }
        u[j] = tpk2(p0, p1);
      }
      // O^T += V^T · P^T in 4 chunks of 8 kv; D regs 4c..4c+3 are B elems 0..3 in-lane
      #pragma unroll
      for (int c = 0; c < 4; ++c) {
        uint2 pu = make_uint2(u[2 * c], u[2 * c + 1]);
        acc[s] = __builtin_amdgcn_mfma_f32_32x32x8bf16_1k(vf[c], bcast<bf16x4>(pu), acc[s], 0, 0, 0);
      }
    }
  }

  // epilogue: lane holds O^T[d = {0..3}+4hi][q], l = acc[4] on hi=0 lanes
  int b = bt / 12, t = bt - b * 12;
  #pragma unroll
  for (int s = 0; s < 2; ++s) {
    float l = __shfl(acc[s][4], lo);
    float inv = __builtin_amdgcn_rcpf(l);
    int q = qbase + s * 32 + lo;
    int g = (h * 12 + t) * 128 + (q >> 2);
    float* ob = obuf + (size_t)blk * 1572864 + ((size_t)b * 6144 + g) * 32 + (q & 3) * 8 + 4 * hi;
    *(float4*)ob = make_float4(acc[s][0] * inv, acc[s][1] * inv, acc[s][2] * inv, acc[s][3] * inv);
  }
}

// ---- epilogue with LDS transpose: out[b][c][t'][n'] = relu(obuf[..] + x[..]) ----
__global__ void __launch_bounds__(256) k_out(const float* __restrict__ x, const float* __restrict__ obuf,
                     float* __restrict__ out) {
  __shared__ float tile[64][65];
  int nc = blockIdx.x;   // 0..7
  int tq = blockIdx.y;   // 0..11
  int b  = blockIdx.z;   // 0..7
  int n0 = nc * 64;
  #pragma unroll
  for (int it = 0; it < 16; ++it) {
    int i = it * 256 + threadIdx.x;
    int nl = i >> 6, c = i & 63;
    int sel = c >> 5;
    tile[nl][c] = obuf[(size_t)sel * 1572864 +
                       ((size_t)b * 6144 + (size_t)(n0 + nl) * 12 + tq) * 32 + (c & 31)];
  }
  __syncthreads();
  #pragma unroll
  for (int it = 0; it < 16; ++it) {
    int i = it * 256 + threadIdx.x;
    int c = i >> 6, nl = i & 63;
    size_t oi = ((size_t)(b * 64 + c) * 12 + tq) * 512 + n0 + nl;
    out[oi] = fmaxf(tile[nl][c] + x[oi], 0.f);
  }
}

extern "C" void kernel_launch(void* const* d_in, const int* in_sizes, int n_in,
                              void* d_out, int out_size, void* d_ws, size_t ws_size,
                              hipStream_t stream) {
  const float* x        = (const float*)d_in[0];
  const int*   geo_mask = (const int*)d_in[1];
  const float* w_proj1  = (const float*)d_in[2];
  const float* b_proj1  = (const float*)d_in[3];
  ProjW pw;
  // blk 0 = plain (x_v), blk 1 = geo (x_geo_v); m: 0=q,1=k,2=v
  pw.w[0] = (const float*)d_in[10]; pw.b[0] = (const float*)d_in[11];  // wq, bq
  pw.w[1] = (const float*)d_in[12]; pw.b[1] = (const float*)d_in[13];  // wk, bk
  pw.w[2] = (const float*)d_in[14]; pw.b[2] = (const float*)d_in[15];  // wv, bv
  pw.w[3] = (const float*)d_in[4];  pw.b[3] = (const float*)d_in[5];   // wgq, bgq
  pw.w[4] = (const float*)d_in[6];  pw.b[4] = (const float*)d_in[7];   // wgk, bgk
  pw.w[5] = (const float*)d_in[8];  pw.b[5] = (const float*)d_in[9];   // wgv, bgv
  float* out = (float*)d_out;

  float* ws = (float*)d_ws;
  float* obuf = ws;                               // [2][8][512][12][32]   = 3,145,728 f32
  float* bfv  = ws + 3145728;                     // [6][32] f32           = 192
  ushort* wfb = (ushort*)(ws + 3145920);          // [192][68] bf16        = 6528 f32
  unsigned* mbw = (unsigned*)(ws + 3152448);      // [512][16] u32         = 8192
  ushort* Qb = (ushort*)(ws + 3160640);           // [2][96][4][512][8]    = 1,572,864 f32
  ushort* Kb = (ushort*)(ws + 4733504);           // same
  ushort* Vt = (ushort*)(ws + 6306368);           // [2][96][4][8][512]

  k_pack_mask<<<32, 256, 0, stream>>>(geo_mask, mbw);
  k_wfuse<<<6, 64, 0, stream>>>(pw, w_proj1, b_proj1, wfb, bfv);
  k_qkv<<<dim3(96, 8), 384, 0, stream>>>(x, wfb, bfv, Qb, Kb, Vt);
  k_attn<<<dim3(4, 96, 2), 512, 0, stream>>>(Qb, Kb, Vt, mbw, obuf);
  k_out<<<dim3(8, 12, 8), 256, 0, stream>>>(x, obuf, out);
}